// Round 5
// baseline (162.804 us; speedup 1.0000x reference)
//
#include <hip/hip_runtime.h>

typedef __attribute__((ext_vector_type(8))) short bf16x8;
typedef __attribute__((ext_vector_type(16))) float f32x16;

#define H 4096
#define W 4096
#define KH 31
#define KW 31
#define OH 4066
#define OW 4066

#define BROWS 32           // output rows per block
#define BCOLS 512          // output cols per block (4 waves x 128)
#define SROWS 47           // staged rows per dy-half pass (32 + 15)
#define SPITCH 576         // padded staged cols (574 used), row = 1152 B
#define SPB 1152

// fp32 -> bf16 round-to-nearest-even
__device__ __forceinline__ unsigned short bf16rne_s(float f) {
    unsigned u = __builtin_bit_cast(unsigned, f);
    u += 0x7fffu + ((u >> 16) & 1u);
    return (unsigned short)(u >> 16);
}

// bf16 A-frag table af[(dy*4 + c)*64 + lane] : bf16x8
//   elem e: K[dy][16c + 8*(lane>>5) + e - (lane&31)], 0 outside band.
__global__ void build_afrag_kernel(const float* __restrict__ Kf,
                                   unsigned short* __restrict__ af) {
    for (int i = threadIdx.x; i < KH * 4 * 64; i += 256) {
        const int dy = i >> 8;
        const int c  = (i >> 6) & 3;
        const int l  = i & 63;
        const int lr = l & 31, lh = l >> 5;
        unsigned short v[8];
        #pragma unroll
        for (int e = 0; e < 8; ++e) {
            const int idx = 16 * c + 8 * lh + e - lr;
            const float f = (idx >= 0 && idx < KW) ? Kf[dy * KW + idx] : 0.0f;
            v[e] = bf16rne_s(f);
        }
        *reinterpret_cast<bf16x8*>(af + (size_t)i * 8) =
            *reinterpret_cast<bf16x8*>(v);
    }
}

__global__ __launch_bounds__(256, 3)
void conv2d_mfma_bf16(const float* __restrict__ X,
                      const unsigned short* __restrict__ af,
                      float* __restrict__ out) {
    __shared__ unsigned short Xs[SROWS * SPITCH];   // 54144 B -> 3 blocks/CU
    char* xsb = (char*)Xs;

    const int tid = threadIdx.x;
    const int l   = tid & 63;
    const int lr  = l & 31;       // B col (= y) lane index
    const int lh  = l >> 5;       // k-half
    const int wv  = tid >> 6;     // 0..3 -> x col group
    const int by0 = blockIdx.y * BROWS;
    const int bx0 = blockIdx.x * BCOLS;
    const int cbase = 128 * wv;

    const bf16x8* A = (const bf16x8*)af;
    f32x16 acc[4] = {};

    #pragma unroll
    for (int h = 0; h < 2; ++h) {
        // ---------- stage 47 input rows [16h, 16h+46]: fp32 -> bf16, swizzled ----
        if (h) __syncthreads();   // wait for all reads of pass 0 before overwrite
        for (int g = tid; g < SROWS * (SPITCH / 4); g += 256) {
            const int r  = g / (SPITCH / 4);
            const int c0 = (g - r * (SPITCH / 4)) * 4;
            const int gy = by0 + 16 * h + r;
            const int gx = bx0 + c0;
            float4 v = make_float4(0.f, 0.f, 0.f, 0.f);
            if (gy < H) {
                const float* row = X + (size_t)gy * W;
                if (gx + 3 < W) {
                    v = *(const float4*)(row + gx);
                } else {
                    if (gx + 0 < W) v.x = row[gx + 0];
                    if (gx + 1 < W) v.y = row[gx + 1];
                    if (gx + 2 < W) v.z = row[gx + 2];
                }
            }
            ushort4 hh;
            hh.x = bf16rne_s(v.x);
            hh.y = bf16rne_s(v.y);
            hh.z = bf16rne_s(v.z);
            hh.w = bf16rne_s(v.w);
            const int byte = r * SPB + c0 * 2;
            *(ushort4*)(xsb + (byte ^ ((r & 7) << 4))) = hh;
        }
        __syncthreads();

        // ---------- compute dy in [16h, 16h+15] (15 dys when h==1) ----------
        const int ndy = h ? 15 : 16;
        for (int dl = 0; dl < ndy; ++dl) {
            const int dy = 16 * h + dl;

            // A-frags: 4 coalesced 16B loads (L1/L2-hot table, same for all waves)
            bf16x8 a[4];
            #pragma unroll
            for (int c = 0; c < 4; ++c) a[c] = A[(dy * 4 + c) * 64 + l];

            // B-frags: 10 sliding 16-wide x-chunks at rows rr = dl + lr
            const int rr = dl + lr;            // <= 46
            const int rowbyte = rr * SPB;
            const int swz = (rr & 7) << 4;
            bf16x8 bb[10];
            #pragma unroll
            for (int m = 0; m < 10; ++m) {
                const int byte = rowbyte + (cbase + 16 * m) * 2 + 16 * lh;
                bb[m] = *(const bf16x8*)(xsb + (byte ^ swz));   // ds_read_b128
            }

            // 4 x-tiles x 4 k-chunks; tile t uses chunks 2t..2t+3
            #pragma unroll
            for (int t = 0; t < 4; ++t) {
                #pragma unroll
                for (int c = 0; c < 4; ++c) {
                    acc[t] = __builtin_amdgcn_mfma_f32_32x32x16_bf16(
                                 a[c], bb[2 * t + c], acc[t], 0, 0, 0);
                }
            }
        }
    }

    // ---------- epilogue: D row = x = (reg&3)+8*(reg>>2)+4*lh, col = y = lr ----
    const int oy = by0 + lr;
    if (oy < OH) {
        float* orow = out + (size_t)oy * OW;
        #pragma unroll
        for (int t = 0; t < 4; ++t) {
            #pragma unroll
            for (int q = 0; q < 4; ++q) {
                const int x = bx0 + cbase + 32 * t + 8 * q + 4 * lh;
                if (x + 3 < OW) {
                    float4 vv = make_float4(acc[t][4*q+0], acc[t][4*q+1],
                                            acc[t][4*q+2], acc[t][4*q+3]);
                    *(float4*)(orow + x) = vv;
                } else {
                    #pragma unroll
                    for (int e = 0; e < 4; ++e)
                        if (x + e < OW) orow[x + e] = acc[t][4*q+e];
                }
            }
        }
    }
}

extern "C" void kernel_launch(void* const* d_in, const int* in_sizes, int n_in,
                              void* d_out, int out_size, void* d_ws, size_t ws_size,
                              hipStream_t stream) {
    const float* X  = (const float*)d_in[0];
    const float* Kf = (const float*)d_in[1];
    float* out = (float*)d_out;
    unsigned short* af = (unsigned short*)d_ws;   // 126976 B

    build_afrag_kernel<<<1, 256, 0, stream>>>(Kf, af);
    dim3 grid((OW + BCOLS - 1) / BCOLS, (OH + BROWS - 1) / BROWS);  // 8 x 128
    conv2d_mfma_bf16<<<grid, dim3(256), 0, stream>>>(X, af, out);
}

// Round 6
// 91.346 us; speedup vs baseline: 1.7823x; 1.7823x over previous
//
#include <hip/hip_runtime.h>

typedef __attribute__((ext_vector_type(4))) short bf16x4;
typedef __attribute__((ext_vector_type(8))) short bf16x8;
typedef __attribute__((ext_vector_type(16))) float f32x16;

#define H 4096
#define W 4096
#define KH 31
#define KW 31
#define OH 4066
#define OW 4066

#define BROWS 32           // output rows per block
#define BCOLS 256          // output cols per block (4 waves x 64)
#define SROWS 62           // BROWS + KH - 1 staged rows
#define SPITCH 320         // padded staged cols, row = 640 B
#define SPB 640

// fp32 -> bf16 round-to-nearest-even
__device__ __forceinline__ unsigned short bf16rne_s(float f) {
    unsigned u = __builtin_bit_cast(unsigned, f);
    u += 0x7fffu + ((u >> 16) & 1u);
    return (unsigned short)(u >> 16);
}

// bf16 A-frag table af[(dy*4 + c)*64 + lane] : bf16x8
//   elem e: K[dy][16c + 8*(lane>>5) + e - (lane&31)], 0 outside band.
__global__ void build_afrag_kernel(const float* __restrict__ Kf,
                                   unsigned short* __restrict__ af) {
    for (int i = threadIdx.x; i < KH * 4 * 64; i += 256) {
        const int dy = i >> 8;
        const int c  = (i >> 6) & 3;
        const int l  = i & 63;
        const int lr = l & 31, lh = l >> 5;
        unsigned short v[8];
        #pragma unroll
        for (int e = 0; e < 8; ++e) {
            const int idx = 16 * c + 8 * lh + e - lr;
            const float f = (idx >= 0 && idx < KW) ? Kf[dy * KW + idx] : 0.0f;
            v[e] = bf16rne_s(f);
        }
        *reinterpret_cast<bf16x8*>(af + (size_t)i * 8) =
            *reinterpret_cast<bf16x8*>(v);
    }
}

// Load A-frags (4 x 16B global, L2-hot) and B-frags (12 x ds_read_b64,
// conflict-free via (rr&15)<<3 swizzle) for one dy into named buffers.
#define LOADF(aX, bX, dy_) do {                                               \
    const int _dy = (dy_);                                                    \
    _Pragma("unroll")                                                         \
    for (int c = 0; c < 4; ++c) aX[c] = A[(_dy * 4 + c) * 64 + l];            \
    const int _rr = _dy + lr;          /* <= 61 */                            \
    const int _rb = _rr * SPB;                                                \
    const int _sw = (_rr & 15) << 3;                                          \
    _Pragma("unroll")                                                         \
    for (int m = 0; m < 6; ++m) {                                             \
        const int _ba = _rb + (cbase + 16 * m) * 2 + 16 * lh;                 \
        bf16x4 _lo = *(const bf16x4*)(xsb + ((_ba    ) ^ _sw));               \
        bf16x4 _hi = *(const bf16x4*)(xsb + ((_ba + 8) ^ _sw));               \
        bX[m] = __builtin_shufflevector(_lo, _hi, 0,1,2,3,4,5,6,7);           \
    }                                                                         \
} while (0)

#define DOMFMA(aX, bX) do {                                                   \
    _Pragma("unroll")                                                         \
    for (int t = 0; t < 2; ++t) {                                             \
        _Pragma("unroll")                                                     \
        for (int c = 0; c < 4; ++c) {                                         \
            acc[t] = __builtin_amdgcn_mfma_f32_32x32x16_bf16(                 \
                         aX[c], bX[2 * t + c], acc[t], 0, 0, 0);              \
        }                                                                     \
    }                                                                         \
} while (0)

__global__ __launch_bounds__(256, 3)
void conv2d_mfma_bf16(const float* __restrict__ X,
                      const unsigned short* __restrict__ af,
                      float* __restrict__ out) {
    __shared__ unsigned short Xs[SROWS * SPITCH];   // 39680 B
    char* xsb = (char*)Xs;

    const int tid = threadIdx.x;
    const int l   = tid & 63;
    const int lr  = l & 31;       // B col (= y) lane index
    const int lh  = l >> 5;       // k-half
    const int wv  = tid >> 6;     // 0..3 -> x col group
    const int by0 = blockIdx.y * BROWS;
    const int bx0 = blockIdx.x * BCOLS;
    const int cbase = 64 * wv;

    // ---------- stage X tile: fp32 -> bf16, 8B-granular XOR swizzle ----------
    for (int g = tid; g < SROWS * (SPITCH / 4); g += 256) {
        const int r  = g / (SPITCH / 4);
        const int c0 = (g - r * (SPITCH / 4)) * 4;
        const int gy = by0 + r;
        const int gx = bx0 + c0;
        float4 v = make_float4(0.f, 0.f, 0.f, 0.f);
        if (gy < H) {
            const float* row = X + (size_t)gy * W;
            if (gx + 3 < W) {
                v = *(const float4*)(row + gx);
            } else {
                if (gx + 0 < W) v.x = row[gx + 0];
                if (gx + 1 < W) v.y = row[gx + 1];
                if (gx + 2 < W) v.z = row[gx + 2];
            }
        }
        ushort4 hh;
        hh.x = bf16rne_s(v.x);
        hh.y = bf16rne_s(v.y);
        hh.z = bf16rne_s(v.z);
        hh.w = bf16rne_s(v.w);
        const int byte = r * SPB + c0 * 2;
        *(ushort4*)(xsb + (byte ^ ((r & 15) << 3))) = hh;
    }
    __syncthreads();

    // ---------- software-pipelined dy loop (no barriers, LDS read-only) ------
    f32x16 acc[2] = {};
    const bf16x8* A = (const bf16x8*)af;

    bf16x8 a0[4], a1[4], b0[6], b1[6];

    LOADF(a0, b0, 0);
    for (int d = 0; d <= 28; d += 2) {
        LOADF(a1, b1, d + 1);   // issue loads for dy+1 before consuming dy
        DOMFMA(a0, b0);
        LOADF(a0, b0, d + 2);   // loads for dy+2 (d=28 -> dy=30, last)
        DOMFMA(a1, b1);
    }
    DOMFMA(a0, b0);             // dy = 30

    // ---------- epilogue: D row = x = (reg&3)+8*(reg>>2)+4*lh, col = y = lr ----
    const int oy = by0 + lr;
    if (oy < OH) {
        float* orow = out + (size_t)oy * OW;
        #pragma unroll
        for (int t = 0; t < 2; ++t) {
            #pragma unroll
            for (int q = 0; q < 4; ++q) {
                const int x = bx0 + cbase + 32 * t + 8 * q + 4 * lh;
                if (x + 3 < OW) {
                    float4 vv = make_float4(acc[t][4*q+0], acc[t][4*q+1],
                                            acc[t][4*q+2], acc[t][4*q+3]);
                    *(float4*)(orow + x) = vv;
                } else {
                    #pragma unroll
                    for (int e = 0; e < 4; ++e)
                        if (x + e < OW) orow[x + e] = acc[t][4*q+e];
                }
            }
        }
    }
}

extern "C" void kernel_launch(void* const* d_in, const int* in_sizes, int n_in,
                              void* d_out, int out_size, void* d_ws, size_t ws_size,
                              hipStream_t stream) {
    const float* X  = (const float*)d_in[0];
    const float* Kf = (const float*)d_in[1];
    float* out = (float*)d_out;
    unsigned short* af = (unsigned short*)d_ws;   // 126976 B

    build_afrag_kernel<<<1, 256, 0, stream>>>(Kf, af);
    dim3 grid((OW + BCOLS - 1) / BCOLS, (OH + BROWS - 1) / BROWS);  // 16 x 128
    conv2d_mfma_bf16<<<grid, dim3(256), 0, stream>>>(X, af, out);
}